// Round 1
// baseline (307.650 us; speedup 1.0000x reference)
//
#include <hip/hip_runtime.h>
#include <stdint.h>

// HashEmbedder (Instant-NGP hash grid), MI355X gfx950.
// Key facts:
//  - Reference truncates output to 16 features => only levels 0..7 needed.
//  - res_l = floor(16 * 2^(l/3)) = {16,20,25,32,40,50,64,80} (hard-coded; f64-exact,
//    matches correctly-rounded f32 pow for the borderline l=3 -> 32, l=6 -> 64).
//  - hash = (bx*1) ^ (by*2654435761) ^ (bz*805459861), masked to 2^19-1.
//  - Trilinear interp continuity makes +-1ulp floor() disagreements harmless.

#define TABLE_SIZE (1u << 19)
#define TMASK (TABLE_SIZE - 1u)
#define P2 2654435761u
#define P3 805459861u

__global__ __launch_bounds__(256) void hash_embed_kernel(
    const float* __restrict__ x, const float* __restrict__ tables,
    float* __restrict__ out, int n)
{
    const int i = blockIdx.x * 256 + threadIdx.x;
    if (i >= n) return;

    const float px = x[3 * i + 0];
    const float py = x[3 * i + 1];
    const float pz = x[3 * i + 2];
    const float cx = fminf(fmaxf(px, 0.0f), 1.0f);
    const float cy = fminf(fmaxf(py, 0.0f), 1.0f);
    const float cz = fminf(fmaxf(pz, 0.0f), 1.0f);

    const float resf[8] = {16.f, 20.f, 25.f, 32.f, 40.f, 50.f, 64.f, 80.f};
    float o[16];

#pragma unroll
    for (int l = 0; l < 8; ++l) {
        const float R = resf[l];
        const float g = 1.0f / R;  // reference's grid = 1/res

        const int bx = (int)floorf(cx * R);
        const int by = (int)floorf(cy * R);
        const int bz = (int)floorf(cz * R);

        // w = (x - vmin) / grid, vmin = bl * grid  (continuity covers ulp diffs)
        const float wx = (px - (float)bx * g) * R;
        const float wy = (py - (float)by * g) * R;
        const float wz = (pz - (float)bz * g) * R;

        const uint32_t hx0 = (uint32_t)bx;          // prime for dim0 is 1
        const uint32_t hx1 = hx0 + 1u;
        const uint32_t hy0 = (uint32_t)by * P2;
        const uint32_t hy1 = hy0 + P2;
        const uint32_t hz0 = (uint32_t)bz * P3;
        const uint32_t hz1 = hz0 + P3;

        const float2* __restrict__ tab =
            (const float2*)(tables + (size_t)l * (size_t)(TABLE_SIZE * 2));

        // OFFSETS row = ix*4 + iy*2 + iz  (ix = x-offset, slowest)
        const float2 e000 = tab[(hx0 ^ hy0 ^ hz0) & TMASK];
        const float2 e001 = tab[(hx0 ^ hy0 ^ hz1) & TMASK];
        const float2 e010 = tab[(hx0 ^ hy1 ^ hz0) & TMASK];
        const float2 e011 = tab[(hx0 ^ hy1 ^ hz1) & TMASK];
        const float2 e100 = tab[(hx1 ^ hy0 ^ hz0) & TMASK];
        const float2 e101 = tab[(hx1 ^ hy0 ^ hz1) & TMASK];
        const float2 e110 = tab[(hx1 ^ hy1 ^ hz0) & TMASK];
        const float2 e111 = tab[(hx1 ^ hy1 ^ hz1) & TMASK];

        const float omx = 1.0f - wx, omy = 1.0f - wy, omz = 1.0f - wz;

        // interp over x (pairs differing in ix), then y, then z — as reference
        const float c00a = e000.x * omx + e100.x * wx;
        const float c00b = e000.y * omx + e100.y * wx;
        const float c01a = e001.x * omx + e101.x * wx;
        const float c01b = e001.y * omx + e101.y * wx;
        const float c10a = e010.x * omx + e110.x * wx;
        const float c10b = e010.y * omx + e110.y * wx;
        const float c11a = e011.x * omx + e111.x * wx;
        const float c11b = e011.y * omx + e111.y * wx;

        const float c0a = c00a * omy + c10a * wy;
        const float c0b = c00b * omy + c10b * wy;
        const float c1a = c01a * omy + c11a * wy;
        const float c1b = c01b * omy + c11b * wy;

        o[2 * l + 0] = c0a * omz + c1a * wz;
        o[2 * l + 1] = c0b * omz + c1b * wz;
    }

    // 64B per point, cacheline-aligned; 4x dwordx4 stores
    float4* __restrict__ op = (float4*)(out + (size_t)i * 16);
    op[0] = make_float4(o[0], o[1], o[2], o[3]);
    op[1] = make_float4(o[4], o[5], o[6], o[7]);
    op[2] = make_float4(o[8], o[9], o[10], o[11]);
    op[3] = make_float4(o[12], o[13], o[14], o[15]);
}

extern "C" void kernel_launch(void* const* d_in, const int* in_sizes, int n_in,
                              void* d_out, int out_size, void* d_ws, size_t ws_size,
                              hipStream_t stream) {
    const float* x = (const float*)d_in[0];
    const float* tables = (const float*)d_in[1];
    float* out = (float*)d_out;
    const int n = in_sizes[0] / 3;  // 1048576 points
    const int block = 256;
    const int grid = (n + block - 1) / block;
    hash_embed_kernel<<<grid, block, 0, stream>>>(x, tables, out, n);
}